// Round 4
// baseline (115.270 us; speedup 1.0000x reference)
//
#include <hip/hip_runtime.h>
#include <hip/hip_fp16.h>
#include <cfloat>
#include <cmath>

#define N_NODES 20000
#define MAXD 32
#define F 128

// fused tiling: one block = 16 nodes (stage1) + its own 16x128 GEMM tile.
// 20000 = 1250 * 16 exactly -> no remainder, no guards, no cross-block deps.
#define MTILE 16
#define NBLK (N_NODES / MTILE)  // 1250 blocks

typedef _Float16 half8 __attribute__((ext_vector_type(8)));
typedef float f32x4 __attribute__((ext_vector_type(4)));
typedef unsigned int u32x4 __attribute__((ext_vector_type(4)));
typedef unsigned short us8v __attribute__((ext_vector_type(8)));

// ---------------- stage-1 core: trimmed-mean aggregation (R11, untouched) ----
// CRITICAL invariants (measured):
//  * node index must be wave-uniform scalar (blockIdx/loop-counter derived) —
//    per-lane i => ~10x VALU blowup (R6: 415us).
//  * private arrays pow2-sized, static indices (R8: else LDS-promote+spill).
//  * one node per 128-thread group; exact-n templates: compile-time b,
//    direct-register rank extraction, pad-pruned sort network.
//  * near the random-gather memory floor (~169 MB scattered 512B segments).
//  * R3 lesson: NO cross-block spin/fence protocols in this harness (container
//    hang). This fusion has zero inter-block dependencies instead.

template <int SZ, int NV>
__device__ __forceinline__ void oe_sort_n(float (&a)[SZ]) {
#pragma unroll
  for (int p = 1; p < SZ; p <<= 1) {
#pragma unroll
    for (int q = p; q >= 1; q >>= 1) {
#pragma unroll
      for (int j = q % p; j <= SZ - 1 - q; j += 2 * q) {
#pragma unroll
        for (int i = 0; i < q; ++i) {
          int x = i + j, y = i + j + q;
          if (y < NV && (x / (2 * p)) == (y / (2 * p))) {  // y<NV ⊆ y<SZ
            float mn = fminf(a[x], a[y]);
            float mx = fmaxf(a[x], a[y]);
            a[x] = mn;
            a[y] = mx;
          }
        }
      }
    }
  }
}

// b = max(min(n/2 - (1-n%2), (int)floor_f32(n*0.45f)), 1) — f32 mult matches
// jnp exactly (e.g. n=20: 20*0.449999988f = 8.9999998 -> 8, not 9).
template <int N>
struct TrimB {
  static constexpr int b_raw = N / 2 - (1 - (N & 1));
  static constexpr int b_cap = (int)((float)N * 0.45f);  // trunc == floor (pos)
  static constexpr int b_min = b_raw < b_cap ? b_raw : b_cap;
  static constexpr int value = b_min > 1 ? b_min : 1;
};

// Exact trimmed sum, exact-n specialization. Stable-rank semantics match
// jnp.argsort (ties by slot). Fast path: no equal-key run straddles either
// trim boundary -> pure value test. Slow path (rare): exact stable-rank scan.
template <int SZ, int N>
__device__ __forceinline__ float trimmed_sum_n(const float* __restrict__ h,
                                               const float* __restrict__ norm,
                                               const int* __restrict__ nbr_row,
                                               int f) {
  constexpr int B = TrimB<N>::value;
  constexpr int NB = N - B;

  float ko[SZ];
  float nrm[SZ];  // wave-uniform addresses -> scalar loads
  float k[SZ];
#pragma unroll
  for (int d = 0; d < N; ++d) {
    int src = nbr_row[d];       // scalar load
    nrm[d] = norm[src];         // scalar load
    ko[d] = h[src * F + f];     // vector load, coalesced 256B/wave
    k[d] = ko[d];
  }
#pragma unroll
  for (int d = N; d < SZ; ++d) k[d] = FLT_MAX;  // pads sort past all valid keys

  oe_sort_n<SZ, N>(k);

  const float lo  = k[B];       // compile-time positions -> direct reg reads
  const float hi  = k[NB - 1];
  const float lom = k[B - 1];
  const float him = k[NB];

  float sum = 0.f;
  if ((lom < lo) & (hi < him)) {
#pragma unroll
    for (int d = 0; d < N; ++d) {
      bool keep = (ko[d] >= lo) & (ko[d] <= hi);
      sum = fmaf(keep ? ko[d] : 0.f, nrm[d], sum);
    }
  } else {
    int c_lt_lo = 0, c_lt_hi = 0;
#pragma unroll
    for (int d = 0; d < N; ++d) {
      c_lt_lo += (ko[d] < lo) ? 1 : 0;
      c_lt_hi += (ko[d] < hi) ? 1 : 0;
    }
    int run_lo = 0, run_hi = 0;
#pragma unroll
    for (int d = 0; d < N; ++d) {
      const float kd = ko[d];
      const float m = kd * nrm[d];
      const bool eql = (kd == lo);
      const bool eqh = (kd == hi);
      const bool lh = (lo < hi);
      const bool btw = (kd > lo) & (kd < hi);
      const int r_lo = c_lt_lo + run_lo;  // stable rank if kd==lo
      const int r_hi = c_lt_hi + run_hi;  // stable rank if kd==hi
      const bool inc = btw
                     | (eql & (r_lo >= B) & (lh | (r_lo < NB)))
                     | (lh & eqh & (r_hi < NB));
      sum += inc ? m : 0.f;
      run_lo += eql ? 1 : 0;
      run_hi += eqh ? 1 : 0;
    }
  }
  return sum;
}

// a = hi + lo captures ~22 mantissa bits; packed into one u32 (hi low16).
__device__ __forceinline__ unsigned int split_pack(float v) {
  _Float16 hi = (_Float16)v;            // rne f32->f16
  _Float16 lo = (_Float16)(v - (float)hi);
  unsigned short hb = __builtin_bit_cast(unsigned short, hi);
  unsigned short lb = __builtin_bit_cast(unsigned short, lo);
  return (unsigned int)hb | ((unsigned int)lb << 16);
}

// ---------------- W pre-split: fp32 [k][n] -> fp16 hi/lo transposed [n][k] ---
// 64 blocks x 256 threads, 1 elem/thread. Thread e=(n,k): read W[k*F+n]
// (scattered 4B, L2-absorbed 64KB), write Whl coalesced 2B consecutive.
__global__ __launch_bounds__(256) void whl_prep(const float* __restrict__ W,
                                                _Float16* __restrict__ Whl) {
  const int e = blockIdx.x * 256 + threadIdx.x;  // e = n*128 + k
  const int n = e >> 7, k = e & 127;
  const float w = W[k * F + n];
  const _Float16 hi = (_Float16)w;
  Whl[e] = hi;
  Whl[16384 + e] = (_Float16)(w - (float)hi);
}

// ---------------- fused kernel: 16-node aggregation + own GEMM tile ----------
// Phase 1: 8 iterations x 2 nodes (each 128-thread half = one node, exactly
// the proven stage-1 structure; i is SGPR: blockIdx*16 + it*2 + hw).
// Rows land in LDS As[16][128] packed u32, XOR-swizzled (idx ^ ((row&7)<<2))
// so the GEMM's 16-lane column reads are 2-way (free) instead of 16-way.
// Phase 2 (after ONE barrier): 16x128 @ 128x128 fp16x2-split MFMA tile
// (R2-refcheck-verified operand/D layouts), B from global Whl (64KB, L2-hot
// in every XCD), out written directly. No Ap workspace, no second dispatch,
// no inter-block sync; GEMM overlaps other blocks' gather latency.
__global__ __launch_bounds__(256) void gcn_fused(
    const float* __restrict__ h, const float* __restrict__ norm,
    const int* __restrict__ nbr, const int* __restrict__ deg,
    const _Float16* __restrict__ Whl, const float* __restrict__ bias,
    float* __restrict__ out) {
  __shared__ unsigned int As[MTILE * F];  // 8 KB, swizzled split-packed rows
  const int tid = threadIdx.x;
  const int hw = __builtin_amdgcn_readfirstlane(tid) >> 7;  // 0/1, SGPR
  const int f = tid & 127;

  // ---------------- phase 1: aggregation for this block's 16 nodes ----------
#pragma unroll 1  // keep ONE copy of the giant switch (I$)
  for (int it = 0; it < 8; ++it) {
    const int nl = it * 2 + hw;                 // node-local 0..15, SGPR
    const int i = blockIdx.x * MTILE + nl;      // global node, SGPR
    const int n = deg[i];
    const float ni = norm[i];
    const float hif = h[i * F + f];

    float val;
    if (n <= 3) {  // N_NEIGH_THRESHOLD branch
      val = (float)n * hif * ni * ni;
    } else {
      const int* nbr_row = nbr + i * MAXD;
      float ts;
      int b;
      switch (n) {
#define TS_CASE(NN, SS) \
        case NN: ts = trimmed_sum_n<SS, NN>(h, norm, nbr_row, f); b = TrimB<NN>::value; break;
        TS_CASE(4, 4)
        TS_CASE(5, 8) TS_CASE(6, 8) TS_CASE(7, 8) TS_CASE(8, 8)
        TS_CASE(9, 16) TS_CASE(10, 16) TS_CASE(11, 16) TS_CASE(12, 16)
        TS_CASE(13, 16) TS_CASE(14, 16) TS_CASE(15, 16) TS_CASE(16, 16)
        TS_CASE(17, 32) TS_CASE(18, 32) TS_CASE(19, 32) TS_CASE(20, 32)
        TS_CASE(21, 32) TS_CASE(22, 32) TS_CASE(23, 32) TS_CASE(24, 32)
        TS_CASE(25, 32) TS_CASE(26, 32) TS_CASE(27, 32) TS_CASE(28, 32)
        TS_CASE(29, 32) TS_CASE(30, 32) TS_CASE(31, 32)
        default: ts = trimmed_sum_n<32, 32>(h, norm, nbr_row, f); b = TrimB<32>::value; break;
#undef TS_CASE
      }
      val = (ts + hif * ni * (float)(2 * b)) * ni;
    }
    // swizzled LDS write: conflict-free (XOR const per node-row)
    As[nl * F + (f ^ ((nl & 7) << 2))] = split_pack(val);
  }

  __syncthreads();  // the only barrier: LDS tile complete

  // ---------------- phase 2: 16x128 fp16x2-split MFMA tile ------------------
  const int lane = tid & 63;
  const int wv = tid >> 6;      // wave -> cols [wv*32, wv*32+32)
  const int l16 = lane & 15;    // A row / B col within fragment
  const int kg = lane >> 4;     // k-group 0..3 (8 k each)
  const int row0 = blockIdx.x * MTILE;
  const int colb = wv * 32;
  const int s = (l16 & 7) << 2; // read-side un-swizzle for row=l16

  f32x4 acc[2];
  acc[0] = (f32x4){0.f, 0.f, 0.f, 0.f};
  acc[1] = (f32x4){0.f, 0.f, 0.f, 0.f};

#pragma unroll
  for (int kc = 0; kc < F; kc += 32) {
    const int k0 = kc + kg * 8;
    // A fragment: rows l16, k = k0..k0+7. Two b128 reads; swizzle maps each
    // 4-aligned group bijectively, retrieving f = k0..k0+7 in order.
    u32x4 p0 = *(const u32x4*)(As + l16 * F + ((k0 + 0) ^ s));
    u32x4 p1 = *(const u32x4*)(As + l16 * F + ((k0 + 4) ^ s));
    us8v s0 = __builtin_bit_cast(us8v, p0);  // {h0,l0,h1,l1,...}
    us8v s1 = __builtin_bit_cast(us8v, p1);
    half8 ah = __builtin_bit_cast(half8,
        (us8v)__builtin_shufflevector(s0, s1, 0, 2, 4, 6, 8, 10, 12, 14));
    half8 al = __builtin_bit_cast(half8,
        (us8v)__builtin_shufflevector(s0, s1, 1, 3, 5, 7, 9, 11, 13, 15));
#pragma unroll
    for (int cf = 0; cf < 2; ++cf) {
      const int n = colb + cf * 16 + l16;
      half8 bh = *(const half8*)(Whl + n * F + k0);
      half8 bl = *(const half8*)(Whl + 16384 + n * F + k0);
      acc[cf] = __builtin_amdgcn_mfma_f32_16x16x32_f16(ah, bh, acc[cf], 0, 0, 0);
      acc[cf] = __builtin_amdgcn_mfma_f32_16x16x32_f16(ah, bl, acc[cf], 0, 0, 0);
      acc[cf] = __builtin_amdgcn_mfma_f32_16x16x32_f16(al, bh, acc[cf], 0, 0, 0);
    }
  }

  // bias + relu. D mapping: col = l16 (+cf*16+colb), row = kg*4 + r
  // (verified C/D layout, m89 + R1/R2 refcheck).
#pragma unroll
  for (int cf = 0; cf < 2; ++cf) {
    const int col = colb + cf * 16 + l16;
    const float bv = bias[col];
#pragma unroll
    for (int r = 0; r < 4; ++r) {
      const int row = row0 + kg * 4 + r;
      out[(size_t)row * F + col] = fmaxf(acc[cf][r] + bv, 0.f);
    }
  }
}

extern "C" void kernel_launch(void* const* d_in, const int* in_sizes, int n_in,
                              void* d_out, int out_size, void* d_ws, size_t ws_size,
                              hipStream_t stream) {
  const float* h = (const float*)d_in[0];
  const float* norm = (const float*)d_in[1];
  const float* weight = (const float*)d_in[2];
  const float* bias = (const float*)d_in[3];
  const int* nbr = (const int*)d_in[4];
  const int* deg = (const int*)d_in[5];
  float* out = (float*)d_out;

  _Float16* Whl = (_Float16*)d_ws;  // 64 KB: split W, hi then lo, [n][k]

  whl_prep<<<64, 256, 0, stream>>>(weight, Whl);
  gcn_fused<<<NBLK, 256, 0, stream>>>(h, norm, nbr, deg, Whl, bias, out);
}